// Round 5
// baseline (542.421 us; speedup 1.0000x reference)
//
#include <hip/hip_runtime.h>
#include <cstddef>

#define NN 100
#define TT 256
#define BB 128
#define SS 7
#define FF 35
#define GG 16

typedef __attribute__((ext_vector_type(4))) float f32x4;
typedef __attribute__((ext_vector_type(8))) short short8;

__constant__ int c_off[5] = {0, -10, 1, 10, -1};

__device__ __forceinline__ float sigmoidf_(float v) {
  return __builtin_amdgcn_rcpf(1.0f + __expf(-v));
}
__device__ __forceinline__ float tanhf_(float v) {
  return 1.0f - 2.0f * __builtin_amdgcn_rcpf(__expf(2.0f * v) + 1.0f);
}
// RNE bf16 pack (setup-time only)
__device__ __forceinline__ unsigned bf1(float a) {
  unsigned u = __float_as_uint(a);
  return (u + 0x7FFFu + ((u >> 16) & 1u)) >> 16;
}
__device__ __forceinline__ unsigned bfp(float lo, float hi) {
  return bf1(lo) | (bf1(hi) << 16);
}
// truncation bf16 pack (hot loop): 2-3 VALU ops
__device__ __forceinline__ unsigned pkt(float lo, float hi) {
  return (__float_as_uint(lo) >> 16) | (__float_as_uint(hi) & 0xFFFF0000u);
}

// ---------------- K1: lm layer 1: H1[b][n][h] = relu(xl @ W1 + b1) ----------------
__global__ void __launch_bounds__(512)
k_lm1(const float* __restrict__ x, const float* __restrict__ W1,
      const float* __restrict__ b1, float* __restrict__ H1) {
  const int bc = blockIdx.x;   // 0..3 (chunk of 32 b)
  const int n  = blockIdx.y;   // 0..99
  const int b0 = bc * 32;
  const int tid = threadIdx.x;
  __shared__ __align__(16) float xl[32][36];
  for (int idx = tid; idx < 32 * FF; idx += 512) {
    const int bb = idx / FF, f = idx % FF;
    const int m = n + c_off[f / SS];
    const int s = f % SS;
    float v = 0.0f;
    if (m >= 0 && m < NN)
      v = x[(((size_t)(b0 + bb) * TT + (TT - 1)) * NN + m) * SS + s];
    xl[bb][f] = v;
  }
  __syncthreads();
  const int h = tid;           // 512 columns
  float w[FF];
  const float* wp = W1 + (size_t)n * FF * 512 + h;
#pragma unroll
  for (int f = 0; f < FF; ++f) w[f] = wp[(size_t)f * 512];
  const float bias = b1[n * 512 + h];
  for (int bb = 0; bb < 32; ++bb) {
    const float4* xr = (const float4*)(&xl[bb][0]);
    float acc = bias;
#pragma unroll
    for (int q = 0; q < 8; ++q) {
      const float4 v = xr[q];
      acc += w[4*q+0] * v.x + w[4*q+1] * v.y + w[4*q+2] * v.z + w[4*q+3] * v.w;
    }
    {
      const float4 v = xr[8];
      acc += w[32] * v.x + w[33] * v.y + w[34] * v.z;
    }
    H1[((size_t)(b0 + bb) * NN + n) * 512 + h] = fmaxf(acc, 0.0f);
  }
}

// ---------------- K2: lm layer 2 via MFMA: H2 = relu(H1 @ W2 + b2) ----------------
// one 16x16 output tile per wave; bf16 (trunc) inputs, fp32 accum.
__global__ void __launch_bounds__(256)
k_lm2(const float* __restrict__ H1, const float* __restrict__ W2,
      const float* __restrict__ bias2, float* __restrict__ H2) {
  const int w  = threadIdx.x >> 6;     // wave 0..3
  const int l  = threadIdx.x & 63;
  const int n  = blockIdx.x >> 5;      // 0..99
  const int tg = blockIdx.x & 31;      // tile group 0..31
  const int tau = tg * 4 + w;          // 0..127
  const int rt = tau >> 4;             // row-tile 0..7
  const int ct = tau & 15;             // col-tile 0..15
  const int lr = l & 15;               // A row / B-C col within tile
  const int kg = l >> 4;               // k-group 0..3

  const int arow = rt * 16 + lr;       // batch row 0..127
  const int col  = ct * 16 + lr;       // out col 0..255

  const float* Ab = H1 + ((size_t)arow * NN + n) * 512 + kg * 8;
  const float* Bb = W2 + (size_t)n * 512 * 256 + (size_t)(kg * 8) * 256 + col;

  f32x4 acc = {0.0f, 0.0f, 0.0f, 0.0f};
#pragma unroll 2
  for (int k0 = 0; k0 < 512; k0 += 32) {
    const float4 a0 = *(const float4*)(Ab + k0);
    const float4 a1 = *(const float4*)(Ab + k0 + 4);
    const float* bp = Bb + (size_t)k0 * 256;
    const float w0 = bp[0],    w1 = bp[256],  w2 = bp[512],  w3 = bp[768];
    const float w4 = bp[1024], w5 = bp[1280], w6 = bp[1536], w7 = bp[1792];
    union { short8 s; unsigned u[4]; } A, B;
    A.u[0] = pkt(a0.x, a0.y); A.u[1] = pkt(a0.z, a0.w);
    A.u[2] = pkt(a1.x, a1.y); A.u[3] = pkt(a1.z, a1.w);
    B.u[0] = pkt(w0, w1); B.u[1] = pkt(w2, w3);
    B.u[2] = pkt(w4, w5); B.u[3] = pkt(w6, w7);
    acc = __builtin_amdgcn_mfma_f32_16x16x32_bf16(A.s, B.s, acc, 0, 0, 0);
  }
  const float bv = bias2[n * 256 + col];
#pragma unroll
  for (int r = 0; r < 4; ++r) {
    const int grow = rt * 16 + kg * 4 + r;   // C row = (l>>4)*4 + r
    H2[((size_t)grow * NN + n) * 256 + col] = fmaxf(acc[r] + bv, 0.0f);
  }
}

// ---------------- K3: lm layer 3: out[n*B+b] = H2 . W3 + b3 ----------------
__global__ void __launch_bounds__(256)
k_lm3(const float* __restrict__ H2, const float* __restrict__ W3,
      const float* __restrict__ b3, float* __restrict__ out) {
  const int w = threadIdx.x >> 6;
  const int lane = threadIdx.x & 63;
  const int p = blockIdx.x * 4 + w;   // 0..12799
  const int b = p / NN, n = p % NN;
  const float4 hv = *(const float4*)(&H2[((size_t)b * NN + n) * 256 + lane*4]);
  const float4 wv = *(const float4*)(&W3[n * 256 + lane*4]);
  float dot = hv.x*wv.x + hv.y*wv.y + hv.z*wv.z + hv.w*wv.w;
#pragma unroll
  for (int off = 32; off > 0; off >>= 1) dot += __shfl_down(dot, off);
  if (lane == 0) out[n * BB + b] = dot + b3[n];
}

// dot-16 with 4 independent partials (chain depth 4 FMA + 2 ADD, not 16 FMA)
__device__ __forceinline__ float dot16s(const float4 u0, const float4 u1,
                                        const float4 u2, const float4 u3,
                                        const float4 h0, const float4 h1,
                                        const float4 h2, const float4 h3) {
  const float p0 = u0.x*h0.x + u0.y*h0.y + u0.z*h0.z + u0.w*h0.w;
  const float p1 = u1.x*h1.x + u1.y*h1.y + u1.z*h1.z + u1.w*h1.w;
  const float p2 = u2.x*h2.x + u2.y*h2.y + u2.z*h2.z + u2.w*h2.w;
  const float p3 = u3.x*h3.x + u3.y*h3.y + u3.z*h3.z + u3.w*h3.w;
  return (p0 + p1) + (p2 + p3);
}

// ---------------- K4: fused GRU (MFMA gi) + sc head; 1 wave per (n, 4 batches) ----------------
__global__ void __launch_bounds__(64, 3)
k_gru(const float* __restrict__ x,
      const float* __restrict__ Wih, const float* __restrict__ Whh,
      const float* __restrict__ bih, const float* __restrict__ bhh,
      const float* __restrict__ sW1, const float* __restrict__ sb1,
      const float* __restrict__ sW2, const float* __restrict__ sb2,
      const float* __restrict__ sW3, const float* __restrict__ sb3,
      float* __restrict__ out) {
  const int l  = threadIdx.x;       // 0..63
  const int g  = l & 15;            // hidden unit (pointwise/gh) ; also B col
  const int b  = l >> 4;            // local batch (pointwise) ; also k-chunk (frags)
  const int kg = b;                 // k-chunk index 0..3 for MFMA fragments
  const int ab = (l & 15) >> 2;     // batch of this lane's A-frag row
  const int atoff = l & 3;          // t-offset of this lane's A-frag row
  const int bc = blockIdx.x;        // 0..31 (chunk of 4 batches)
  const int n  = blockIdx.y;        // 0..99
  const int bga = bc*4 + ab;        // A-load global batch
  const int bgp = bc*4 + b;         // pointwise global batch

  __shared__ float hlds[4][16];

  // ---- Whh rows g, 16+g, 32+g in registers (fp32) ----
  const float* wh = Whh + ((size_t)n*48 + g)*GG;
  const float4 ur0 = *(const float4*)(wh+0),  ur1 = *(const float4*)(wh+4),
               ur2 = *(const float4*)(wh+8),  ur3 = *(const float4*)(wh+12);
  const float4 uz0 = *(const float4*)(wh+256),  uz1 = *(const float4*)(wh+260),
               uz2 = *(const float4*)(wh+264),  uz3 = *(const float4*)(wh+268);
  const float4 un0 = *(const float4*)(wh+512),  un1 = *(const float4*)(wh+516),
               un2 = *(const float4*)(wh+520),  un3 = *(const float4*)(wh+524);
  const float bir = bih[n*48 + g], biz = bih[n*48 + 16 + g], bin_ = bih[n*48 + 32 + g];
  const float bhr = bhh[n*48 + g], bhz = bhh[n*48 + 16 + g], bhn = bhh[n*48 + 32 + g];

  // ---- B fragments (Wih^T), bf16 RNE: lane holds B[k = kg*8+j][col = g] per gate-tile c ----
  short8 bw[3], bw2[3];
#pragma unroll
  for (int c = 0; c < 3; ++c) {
    const float* wp = Wih + ((size_t)n*48 + c*16 + g)*FF;
    float t0_[8], t1_[8];
#pragma unroll
    for (int j = 0; j < 8; ++j) t0_[j] = wp[kg*8 + j];             // k = 0..31 all < 35
#pragma unroll
    for (int j = 0; j < 8; ++j) {
      const int k2 = 32 + kg*8 + j;
      t1_[j] = (k2 < FF) ? wp[k2] : 0.0f;
    }
    union { short8 s; unsigned u[4]; } U, V;
#pragma unroll
    for (int jj = 0; jj < 4; ++jj) { U.u[jj] = bfp(t0_[2*jj], t0_[2*jj+1]);
                                     V.u[jj] = bfp(t1_[2*jj], t1_[2*jj+1]); }
    bw[c] = U.s; bw2[c] = V.s;
  }

  // ---- per-lane A-load metadata: row (ab, atoff), k = kg*8 + j ----
  int adelta[8]; unsigned amask = 0;
#pragma unroll
  for (int j = 0; j < 8; ++j) {
    const int f  = kg*8 + j;             // 0..31
    const int fi = (f * 586) >> 12;      // f / 7
    const int s  = f - fi*7;
    const int mo = (fi == 0) ? 0 : (fi == 1) ? -10 : (fi == 2) ? 1 : (fi == 3) ? 10 : -1;
    adelta[j] = mo*SS + s;
    const int m = n + mo;
    if (m >= 0 && m < NN) amask |= (1u << j);
  }
  const bool v2 = (kg == 0) && (n >= 1);  // frag2: k=32..34 -> offset -1, s=4..6

  // ---- initial prefetch (round 0: lane's row is timestep atoff) ----
  float xv[8], xv2[3];
  {
    const float* xq = x + ((size_t)bga*TT + atoff)*(NN*SS) + n*SS;
#pragma unroll
    for (int j = 0; j < 8; ++j) xv[j] = ((amask >> j) & 1u) ? xq[adelta[j]] : 0.0f;
#pragma unroll
    for (int j = 0; j < 3; ++j) xv2[j] = v2 ? xq[-3 + j] : 0.0f;
  }

  hlds[b][g] = 0.0f;
  float hown = 0.0f;

  const f32x4 z4 = {0.0f, 0.0f, 0.0f, 0.0f};

  for (int rd = 0; rd < TT/4; ++rd) {
    // build A fragments (truncation pack: cheap)
    union { short8 s; unsigned u[4]; } A1, A2;
#pragma unroll
    for (int jj = 0; jj < 4; ++jj) A1.u[jj] = pkt(xv[2*jj], xv[2*jj+1]);
    A2.u[0] = pkt(xv2[0], xv2[1]); A2.u[1] = pkt(xv2[2], 0.0f); A2.u[2] = 0; A2.u[3] = 0;
    const short8 af1 = A1.s, af2 = A2.s;

    // prefetch next round (timestep = (rd+1)*4 + atoff)
    if (rd < TT/4 - 1) {
      const float* xq = x + ((size_t)bga*TT + (rd*4 + 4 + atoff))*(NN*SS) + n*SS;
#pragma unroll
      for (int j = 0; j < 8; ++j) xv[j] = ((amask >> j) & 1u) ? xq[adelta[j]] : 0.0f;
#pragma unroll
      for (int j = 0; j < 3; ++j) xv2[j] = v2 ? xq[-3 + j] : 0.0f;
    }

    // gi for 4 batches x 4 timesteps x 48 gates: C row = batch*4 + toff
    f32x4 c0 = __builtin_amdgcn_mfma_f32_16x16x32_bf16(af1, bw[0], z4, 0, 0, 0);
    c0 = __builtin_amdgcn_mfma_f32_16x16x32_bf16(af2, bw2[0], c0, 0, 0, 0);
    f32x4 c1 = __builtin_amdgcn_mfma_f32_16x16x32_bf16(af1, bw[1], z4, 0, 0, 0);
    c1 = __builtin_amdgcn_mfma_f32_16x16x32_bf16(af2, bw2[1], c1, 0, 0, 0);
    f32x4 c2 = __builtin_amdgcn_mfma_f32_16x16x32_bf16(af1, bw[2], z4, 0, 0, 0);
    c2 = __builtin_amdgcn_mfma_f32_16x16x32_bf16(af2, bw2[2], c2, 0, 0, 0);

    // 4 recurrent steps; lane holds (b = l>>4, g = l&15), gi at frag element toff
#pragma unroll
    for (int toff = 0; toff < 4; ++toff) {
      const float ir  = c0[toff] + bir;
      const float iz  = c1[toff] + biz;
      const float in_ = c2[toff] + bin_;
      const float4* hp = (const float4*)(&hlds[b][0]);
      const float4 h0 = hp[0], h1 = hp[1], h2 = hp[2], h3 = hp[3];
      const float hr = bhr + dot16s(ur0, ur1, ur2, ur3, h0, h1, h2, h3);
      const float hz = bhz + dot16s(uz0, uz1, uz2, uz3, h0, h1, h2, h3);
      const float hn = bhn + dot16s(un0, un1, un2, un3, h0, h1, h2, h3);
      const float r   = sigmoidf_(ir + hr);
      const float z   = sigmoidf_(iz + hz);
      const float nn2 = tanhf_(in_ + r * hn);
      const float hnew = nn2 + z * (hown - nn2);
      hlds[b][g] = hnew;
      hown = hnew;
    }
  }

  // ----- sc head: 16 -> 16 -> 16 -> 1 (wave-local, LDS exchange) -----
  {
    const float4* hp = (const float4*)(&hlds[b][0]);
    const float4 h0 = hp[0], h1 = hp[1], h2 = hp[2], h3 = hp[3];
    const float* w1 = sW1 + n*GG*GG + g;
    float a1 = sb1[n*GG + g];
    a1 += h0.x*w1[0*GG] + h0.y*w1[1*GG] + h0.z*w1[2*GG] + h0.w*w1[3*GG];
    a1 += h1.x*w1[4*GG] + h1.y*w1[5*GG] + h1.z*w1[6*GG] + h1.w*w1[7*GG];
    a1 += h2.x*w1[8*GG] + h2.y*w1[9*GG] + h2.z*w1[10*GG] + h2.w*w1[11*GG];
    a1 += h3.x*w1[12*GG] + h3.y*w1[13*GG] + h3.z*w1[14*GG] + h3.w*w1[15*GG];
    a1 = fmaxf(a1, 0.0f);
    hlds[b][g] = a1;
  }
  {
    const float4* hp = (const float4*)(&hlds[b][0]);
    const float4 h0 = hp[0], h1 = hp[1], h2 = hp[2], h3 = hp[3];
    const float* w2 = sW2 + n*GG*GG + g;
    float a2 = sb2[n*GG + g];
    a2 += h0.x*w2[0*GG] + h0.y*w2[1*GG] + h0.z*w2[2*GG] + h0.w*w2[3*GG];
    a2 += h1.x*w2[4*GG] + h1.y*w2[5*GG] + h1.z*w2[6*GG] + h1.w*w2[7*GG];
    a2 += h2.x*w2[8*GG] + h2.y*w2[9*GG] + h2.z*w2[10*GG] + h2.w*w2[11*GG];
    a2 += h3.x*w2[12*GG] + h3.y*w2[13*GG] + h3.z*w2[14*GG] + h3.w*w2[15*GG];
    a2 = fmaxf(a2, 0.0f);
    // q = sum_k a2[b][k] * sW3[n][k]  (reduce across the 16-lane group)
    float p = a2 * sW3[n*GG + g];
    p += __shfl_xor(p, 1);
    p += __shfl_xor(p, 2);
    p += __shfl_xor(p, 4);
    p += __shfl_xor(p, 8);
    if (g == 0) out[n * BB + bgp] += p + sb3[n];
  }
}

extern "C" void kernel_launch(void* const* d_in, const int* in_sizes, int n_in,
                              void* d_out, int out_size, void* d_ws, size_t ws_size,
                              hipStream_t stream) {
  const float* x     = (const float*)d_in[0];
  const float* lm_W1 = (const float*)d_in[1];
  const float* lm_b1 = (const float*)d_in[2];
  const float* lm_W2 = (const float*)d_in[3];
  const float* lm_b2 = (const float*)d_in[4];
  const float* lm_W3 = (const float*)d_in[5];
  const float* lm_b3 = (const float*)d_in[6];
  const float* gWih  = (const float*)d_in[7];
  const float* gWhh  = (const float*)d_in[8];
  const float* gbih  = (const float*)d_in[9];
  const float* gbhh  = (const float*)d_in[10];
  const float* sW1   = (const float*)d_in[11];
  const float* sb1   = (const float*)d_in[12];
  const float* sW2   = (const float*)d_in[13];
  const float* sb2   = (const float*)d_in[14];
  const float* sW3   = (const float*)d_in[15];
  const float* sb3   = (const float*)d_in[16];
  float* out = (float*)d_out;

  float* H1 = (float*)d_ws;                                       // 128*100*512 f32 = 26.2 MB
  float* H2 = (float*)((char*)d_ws + (size_t)BB * NN * 512 * 4);  // 128*100*256 f32 = 13.1 MB

  k_lm1<<<dim3(4, NN), 512, 0, stream>>>(x, lm_W1, lm_b1, H1);
  k_lm2<<<dim3(3200), 256, 0, stream>>>(H1, lm_W2, lm_b2, H2);
  k_lm3<<<dim3(3200), 256, 0, stream>>>(H2, lm_W3, lm_b3, out);
  k_gru<<<dim3(32, NN), 64, 0, stream>>>(x, gWih, gWhh, gbih, gbhh,
                                         sW1, sb1, sW2, sb2, sW3, sb3, out);
}

// Round 10
// 490.890 us; speedup vs baseline: 1.1050x; 1.1050x over previous
//
#include <hip/hip_runtime.h>
#include <cstddef>

#define NN 100
#define TT 256
#define BB 128
#define SS 7
#define FF 35
#define GG 16

typedef __attribute__((ext_vector_type(4))) float f32x4;
typedef __attribute__((ext_vector_type(8))) short short8;

__constant__ int c_off[5] = {0, -10, 1, 10, -1};

__device__ __forceinline__ float sigmoidf_(float v) {
  return __builtin_amdgcn_rcpf(1.0f + __expf(-v));
}
__device__ __forceinline__ float tanhf_(float v) {
  return 1.0f - 2.0f * __builtin_amdgcn_rcpf(__expf(2.0f * v) + 1.0f);
}
// RNE bf16 pack (setup-time only)
__device__ __forceinline__ unsigned bf1(float a) {
  unsigned u = __float_as_uint(a);
  return (u + 0x7FFFu + ((u >> 16) & 1u)) >> 16;
}
__device__ __forceinline__ unsigned bfp(float lo, float hi) {
  return bf1(lo) | (bf1(hi) << 16);
}
// truncation bf16 pack (hot loop)
__device__ __forceinline__ unsigned pkt(float lo, float hi) {
  return (__float_as_uint(lo) >> 16) | (__float_as_uint(hi) & 0xFFFF0000u);
}

// DPP row-rotate-right by literal J (within 16-lane rows)
#define RORF(dst, src, J)                                                     \
  dst = __uint_as_float(__builtin_amdgcn_update_dpp(                          \
      0, (int)__float_as_uint(src), 0x120 + (J), 0xF, 0xF, true));

// ---------------- K1: lm layer 1: H1[b][n][h] = relu(xl @ W1 + b1) ----------------
__global__ void __launch_bounds__(512)
k_lm1(const float* __restrict__ x, const float* __restrict__ W1,
      const float* __restrict__ b1, float* __restrict__ H1) {
  const int bc = blockIdx.x;   // 0..3 (chunk of 32 b)
  const int n  = blockIdx.y;   // 0..99
  const int b0 = bc * 32;
  const int tid = threadIdx.x;
  __shared__ __align__(16) float xl[32][36];
  for (int idx = tid; idx < 32 * FF; idx += 512) {
    const int bb = idx / FF, f = idx % FF;
    const int m = n + c_off[f / SS];
    const int s = f % SS;
    float v = 0.0f;
    if (m >= 0 && m < NN)
      v = x[(((size_t)(b0 + bb) * TT + (TT - 1)) * NN + m) * SS + s];
    xl[bb][f] = v;
  }
  __syncthreads();
  const int h = tid;           // 512 columns
  float w[FF];
  const float* wp = W1 + (size_t)n * FF * 512 + h;
#pragma unroll
  for (int f = 0; f < FF; ++f) w[f] = wp[(size_t)f * 512];
  const float bias = b1[n * 512 + h];
  for (int bb = 0; bb < 32; ++bb) {
    const float4* xr = (const float4*)(&xl[bb][0]);
    float acc = bias;
#pragma unroll
    for (int q = 0; q < 8; ++q) {
      const float4 v = xr[q];
      acc += w[4*q+0] * v.x + w[4*q+1] * v.y + w[4*q+2] * v.z + w[4*q+3] * v.w;
    }
    {
      const float4 v = xr[8];
      acc += w[32] * v.x + w[33] * v.y + w[34] * v.z;
    }
    H1[((size_t)(b0 + bb) * NN + n) * 512 + h] = fmaxf(acc, 0.0f);
  }
}

// ---------------- K2 v3: H2 = relu(H1 @ W2 + b2); 64x64 tile, A in LDS (bf16), B direct ----------------
__global__ void __launch_bounds__(256)
k_lm2(const float* __restrict__ H1, const float* __restrict__ W2,
      const float* __restrict__ bias2, float* __restrict__ H2) {
  const int n  = blockIdx.x;          // 0..99
  const int bh = blockIdx.y >> 2;     // 0..1 : 64-row half
  const int ch = blockIdx.y & 3;      // 0..3 : 64-col quarter
  const int t  = threadIdx.x;
  const int w  = t >> 6;              // wave 0..3
  const int l  = t & 63;
  const int lr = l & 15;
  const int kg = l >> 4;              // 0..3
  const int m0 = (w >> 1) * 32;       // wave row offset in tile
  const int c0 = (w & 1) * 32;        // wave col offset in tile

  __shared__ __align__(16) unsigned short As[64][72];  // bf16, padded

  f32x4 acc00 = {0,0,0,0}, acc01 = {0,0,0,0}, acc10 = {0,0,0,0}, acc11 = {0,0,0,0};

  const int colg0 = ch * 64 + c0;
  const float* Bbase = W2 + (size_t)n * 512 * 256;

  for (int k0 = 0; k0 < 512; k0 += 64) {
    __syncthreads();
#pragma unroll
    for (int q = 0; q < 4; ++q) {
      const int idx = t + q * 256;    // 0..1023
      const int row = idx >> 4;       // 0..63
      const int kq  = idx & 15;       // 0..15
      const float4 v = *(const float4*)(&H1[((size_t)(bh*64 + row) * NN + n) * 512 + k0 + kq*4]);
      uint2 pv; pv.x = pkt(v.x, v.y); pv.y = pkt(v.z, v.w);
      *(uint2*)(&As[row][kq*4]) = pv;
    }
    __syncthreads();
#pragma unroll
    for (int kc = 0; kc < 2; ++kc) {
      const short8 a0 = *(const short8*)(&As[m0 + lr][kc*32 + kg*8]);
      const short8 a1 = *(const short8*)(&As[m0 + 16 + lr][kc*32 + kg*8]);
      union { short8 s; unsigned u[4]; } B0, B1;
      const float* bp0 = Bbase + (size_t)(k0 + kc*32 + kg*8) * 256 + colg0 + lr;
      const float* bp1 = bp0 + 16;
#pragma unroll
      for (int jj = 0; jj < 4; ++jj) {
        B0.u[jj] = pkt(bp0[(size_t)(2*jj)*256], bp0[(size_t)(2*jj+1)*256]);
        B1.u[jj] = pkt(bp1[(size_t)(2*jj)*256], bp1[(size_t)(2*jj+1)*256]);
      }
      acc00 = __builtin_amdgcn_mfma_f32_16x16x32_bf16(a0, B0.s, acc00, 0, 0, 0);
      acc01 = __builtin_amdgcn_mfma_f32_16x16x32_bf16(a0, B1.s, acc01, 0, 0, 0);
      acc10 = __builtin_amdgcn_mfma_f32_16x16x32_bf16(a1, B0.s, acc10, 0, 0, 0);
      acc11 = __builtin_amdgcn_mfma_f32_16x16x32_bf16(a1, B1.s, acc11, 0, 0, 0);
    }
  }
  const int colA = colg0 + lr, colB = colA + 16;
  const float bva = bias2[n*256 + colA], bvb = bias2[n*256 + colB];
#pragma unroll
  for (int r = 0; r < 4; ++r) {
    const int rowA = bh*64 + m0 + kg*4 + r;
    const int rowB = rowA + 16;
    H2[((size_t)rowA * NN + n) * 256 + colA] = fmaxf(acc00[r] + bva, 0.0f);
    H2[((size_t)rowA * NN + n) * 256 + colB] = fmaxf(acc01[r] + bvb, 0.0f);
    H2[((size_t)rowB * NN + n) * 256 + colA] = fmaxf(acc10[r] + bva, 0.0f);
    H2[((size_t)rowB * NN + n) * 256 + colB] = fmaxf(acc11[r] + bvb, 0.0f);
  }
}

// ---------------- K3: lm layer 3: out[n*B+b] = H2 . W3 + b3 ----------------
__global__ void __launch_bounds__(256)
k_lm3(const float* __restrict__ H2, const float* __restrict__ W3,
      const float* __restrict__ b3, float* __restrict__ out) {
  const int w = threadIdx.x >> 6;
  const int lane = threadIdx.x & 63;
  const int p = blockIdx.x * 4 + w;   // 0..12799
  const int b = p / NN, n = p % NN;
  const float4 hv = *(const float4*)(&H2[((size_t)b * NN + n) * 256 + lane*4]);
  const float4 wv = *(const float4*)(&W3[n * 256 + lane*4]);
  float dot = hv.x*wv.x + hv.y*wv.y + hv.z*wv.z + hv.w*wv.w;
#pragma unroll
  for (int off = 32; off > 0; off >>= 1) dot += __shfl_down(dot, off);
  if (lane == 0) out[n * BB + b] = dot + b3[n];
}

// ---------------- K4: fused GRU (MFMA gi, DPP-rotate gh) + sc head ----------------
__global__ void __launch_bounds__(64, 3)
k_gru(const float* __restrict__ x,
      const float* __restrict__ Wih, const float* __restrict__ Whh,
      const float* __restrict__ bih, const float* __restrict__ bhh,
      const float* __restrict__ sW1, const float* __restrict__ sb1,
      const float* __restrict__ sW2, const float* __restrict__ sb2,
      const float* __restrict__ sW3, const float* __restrict__ sb3,
      float* __restrict__ out) {
  const int l  = threadIdx.x;       // 0..63
  const int g  = l & 15;            // hidden unit (pointwise) ; also B col
  const int b  = l >> 4;            // local batch (pointwise) ; also k-chunk (frags)
  const int kg = b;                 // k-chunk index 0..3 for MFMA fragments
  const int ab = (l & 15) >> 2;     // batch of this lane's A-frag row
  const int atoff = l & 3;          // t-offset of this lane's A-frag row
  const int bc = blockIdx.x;        // 0..31 (chunk of 4 batches)
  const int n  = blockIdx.y;        // 0..99
  const int bga = bc*4 + ab;        // A-load global batch
  const int bgp = bc*4 + b;         // pointwise global batch

  // ---- DPP rotation direction probe: after ROW_ROR:1, which neighbor did we get? ----
  const int wpr = __builtin_amdgcn_update_dpp(0, g, 0x121, 0xF, 0xF, true);
  const int s   = (wpr == ((g + 15) & 15)) ? -1 : 1;  // rotation j delivers h[(g + s*j)&15]

  // ---- Whh rows g, 16+g, 32+g, permuted so coeff j matches rotation j ----
  const float* whr = Whh + ((size_t)n*48 +      g) * GG;
  const float* whz = Whh + ((size_t)n*48 + 16 + g) * GG;
  const float* whn = Whh + ((size_t)n*48 + 32 + g) * GG;
  float ur[16], uz[16], un[16];
#pragma unroll
  for (int j = 0; j < 16; ++j) {
    const int ix = (g + s*j) & 15;
    ur[j] = whr[ix]; uz[j] = whz[ix]; un[j] = whn[ix];
  }
  const float bir = bih[n*48 + g], biz = bih[n*48 + 16 + g], bin_ = bih[n*48 + 32 + g];
  const float bhr = bhh[n*48 + g], bhz = bhh[n*48 + 16 + g], bhn = bhh[n*48 + 32 + g];

  // ---- B fragments (Wih^T), bf16 RNE: lane holds B[k = kg*8+j][col = g] per gate-tile c ----
  short8 bw[3], bw2[3];
#pragma unroll
  for (int c = 0; c < 3; ++c) {
    const float* wp = Wih + ((size_t)n*48 + c*16 + g)*FF;
    float t0_[8], t1_[8];
#pragma unroll
    for (int j = 0; j < 8; ++j) t0_[j] = wp[kg*8 + j];
#pragma unroll
    for (int j = 0; j < 8; ++j) {
      const int k2 = 32 + kg*8 + j;
      t1_[j] = (k2 < FF) ? wp[k2] : 0.0f;
    }
    union { short8 s8; unsigned u[4]; } U, V;
#pragma unroll
    for (int jj = 0; jj < 4; ++jj) { U.u[jj] = bfp(t0_[2*jj], t0_[2*jj+1]);
                                     V.u[jj] = bfp(t1_[2*jj], t1_[2*jj+1]); }
    bw[c] = U.s8; bw2[c] = V.s8;
  }

  // ---- per-lane A-load metadata ----
  int adelta[8]; unsigned amask = 0;
#pragma unroll
  for (int j = 0; j < 8; ++j) {
    const int f  = kg*8 + j;
    const int fi = (f * 586) >> 12;      // f / 7
    const int sg = f - fi*7;
    const int mo = (fi == 0) ? 0 : (fi == 1) ? -10 : (fi == 2) ? 1 : (fi == 3) ? 10 : -1;
    adelta[j] = mo*SS + sg;
    const int m = n + mo;
    if (m >= 0 && m < NN) amask |= (1u << j);
  }
  const bool v2 = (kg == 0) && (n >= 1);

  // ---- initial prefetch (round 0: lane's row is timestep atoff) ----
  float xv[8], xv2[3];
  {
    const float* xq = x + ((size_t)bga*TT + atoff)*(NN*SS) + n*SS;
#pragma unroll
    for (int j = 0; j < 8; ++j) xv[j] = ((amask >> j) & 1u) ? xq[adelta[j]] : 0.0f;
#pragma unroll
    for (int j = 0; j < 3; ++j) xv2[j] = v2 ? xq[-3 + j] : 0.0f;
  }

  float hown = 0.0f;
  const f32x4 z4 = {0.0f, 0.0f, 0.0f, 0.0f};

  for (int rd = 0; rd < TT/4; ++rd) {
    union { short8 s8; unsigned u[4]; } A1, A2;
#pragma unroll
    for (int jj = 0; jj < 4; ++jj) A1.u[jj] = pkt(xv[2*jj], xv[2*jj+1]);
    A2.u[0] = pkt(xv2[0], xv2[1]); A2.u[1] = pkt(xv2[2], 0.0f); A2.u[2] = 0; A2.u[3] = 0;
    const short8 af1 = A1.s8, af2 = A2.s8;

    if (rd < TT/4 - 1) {
      const float* xq = x + ((size_t)bga*TT + (rd*4 + 4 + atoff))*(NN*SS) + n*SS;
#pragma unroll
      for (int j = 0; j < 8; ++j) xv[j] = ((amask >> j) & 1u) ? xq[adelta[j]] : 0.0f;
#pragma unroll
      for (int j = 0; j < 3; ++j) xv2[j] = v2 ? xq[-3 + j] : 0.0f;
    }

    f32x4 c0 = __builtin_amdgcn_mfma_f32_16x16x32_bf16(af1, bw[0], z4, 0, 0, 0);
    c0 = __builtin_amdgcn_mfma_f32_16x16x32_bf16(af2, bw2[0], c0, 0, 0, 0);
    f32x4 c1 = __builtin_amdgcn_mfma_f32_16x16x32_bf16(af1, bw[1], z4, 0, 0, 0);
    c1 = __builtin_amdgcn_mfma_f32_16x16x32_bf16(af2, bw2[1], c1, 0, 0, 0);
    f32x4 c2 = __builtin_amdgcn_mfma_f32_16x16x32_bf16(af1, bw[2], z4, 0, 0, 0);
    c2 = __builtin_amdgcn_mfma_f32_16x16x32_bf16(af2, bw2[2], c2, 0, 0, 0);

#pragma unroll
    for (int toff = 0; toff < 4; ++toff) {
      // rotate current h across the 16-lane row (VALU-only, no LDS)
      float h1, h2, h3, h4, h5, h6, h7, h8, h9, h10, h11, h12, h13, h14, h15;
      RORF(h1,  hown, 1)  RORF(h2,  hown, 2)  RORF(h3,  hown, 3)
      RORF(h4,  hown, 4)  RORF(h5,  hown, 5)  RORF(h6,  hown, 6)
      RORF(h7,  hown, 7)  RORF(h8,  hown, 8)  RORF(h9,  hown, 9)
      RORF(h10, hown, 10) RORF(h11, hown, 11) RORF(h12, hown, 12)
      RORF(h13, hown, 13) RORF(h14, hown, 14) RORF(h15, hown, 15)

      float pr0 = ur[0]*hown + ur[1]*h1  + ur[2]*h2  + ur[3]*h3;
      float pr1 = ur[4]*h4   + ur[5]*h5  + ur[6]*h6  + ur[7]*h7;
      float pr2 = ur[8]*h8   + ur[9]*h9  + ur[10]*h10 + ur[11]*h11;
      float pr3 = ur[12]*h12 + ur[13]*h13 + ur[14]*h14 + ur[15]*h15;
      const float hr = bhr + ((pr0 + pr1) + (pr2 + pr3));

      float pz0 = uz[0]*hown + uz[1]*h1  + uz[2]*h2  + uz[3]*h3;
      float pz1 = uz[4]*h4   + uz[5]*h5  + uz[6]*h6  + uz[7]*h7;
      float pz2 = uz[8]*h8   + uz[9]*h9  + uz[10]*h10 + uz[11]*h11;
      float pz3 = uz[12]*h12 + uz[13]*h13 + uz[14]*h14 + uz[15]*h15;
      const float hz = bhz + ((pz0 + pz1) + (pz2 + pz3));

      float pn0 = un[0]*hown + un[1]*h1  + un[2]*h2  + un[3]*h3;
      float pn1 = un[4]*h4   + un[5]*h5  + un[6]*h6  + un[7]*h7;
      float pn2 = un[8]*h8   + un[9]*h9  + un[10]*h10 + un[11]*h11;
      float pn3 = un[12]*h12 + un[13]*h13 + un[14]*h14 + un[15]*h15;
      const float hn = bhn + ((pn0 + pn1) + (pn2 + pn3));

      const float r   = sigmoidf_(c0[toff] + bir + hr);
      const float z   = sigmoidf_(c1[toff] + biz + hz);
      const float nn2 = tanhf_(c2[toff] + bin_ + r * hn);
      hown = nn2 + z * (hown - nn2);
    }
  }

  // ----- sc head: 16 -> 16 -> 16 -> 1, same DPP rotation trick -----
  float a1;
  {
    float h1, h2, h3, h4, h5, h6, h7, h8, h9, h10, h11, h12, h13, h14, h15;
    RORF(h1,  hown, 1)  RORF(h2,  hown, 2)  RORF(h3,  hown, 3)
    RORF(h4,  hown, 4)  RORF(h5,  hown, 5)  RORF(h6,  hown, 6)
    RORF(h7,  hown, 7)  RORF(h8,  hown, 8)  RORF(h9,  hown, 9)
    RORF(h10, hown, 10) RORF(h11, hown, 11) RORF(h12, hown, 12)
    RORF(h13, hown, 13) RORF(h14, hown, 14) RORF(h15, hown, 15)
    const float* w1 = sW1 + n*GG*GG;
    float acc = sb1[n*GG + g];
    const float hv[16] = {hown,h1,h2,h3,h4,h5,h6,h7,h8,h9,h10,h11,h12,h13,h14,h15};
#pragma unroll
    for (int j = 0; j < 16; ++j) {
      const int ix = (g + s*j) & 15;    // rotation j carries h[ix]
      acc += hv[j] * w1[ix*GG + g];
    }
    a1 = fmaxf(acc, 0.0f);
  }
  float a2;
  {
    float h1, h2, h3, h4, h5, h6, h7, h8, h9, h10, h11, h12, h13, h14, h15;
    RORF(h1,  a1, 1)  RORF(h2,  a1, 2)  RORF(h3,  a1, 3)
    RORF(h4,  a1, 4)  RORF(h5,  a1, 5)  RORF(h6,  a1, 6)
    RORF(h7,  a1, 7)  RORF(h8,  a1, 8)  RORF(h9,  a1, 9)
    RORF(h10, a1, 10) RORF(h11, a1, 11) RORF(h12, a1, 12)
    RORF(h13, a1, 13) RORF(h14, a1, 14) RORF(h15, a1, 15)
    const float* w2 = sW2 + n*GG*GG;
    float acc = sb2[n*GG + g];
    const float hv[16] = {a1,h1,h2,h3,h4,h5,h6,h7,h8,h9,h10,h11,h12,h13,h14,h15};
#pragma unroll
    for (int j = 0; j < 16; ++j) {
      const int ix = (g + s*j) & 15;
      acc += hv[j] * w2[ix*GG + g];
    }
    a2 = fmaxf(acc, 0.0f);
  }
  {
    float p = a2 * sW3[n*GG + g];
    p += __shfl_xor(p, 1);
    p += __shfl_xor(p, 2);
    p += __shfl_xor(p, 4);
    p += __shfl_xor(p, 8);
    if (g == 0) out[n * BB + bgp] += p + sb3[n];
  }
}

extern "C" void kernel_launch(void* const* d_in, const int* in_sizes, int n_in,
                              void* d_out, int out_size, void* d_ws, size_t ws_size,
                              hipStream_t stream) {
  const float* x     = (const float*)d_in[0];
  const float* lm_W1 = (const float*)d_in[1];
  const float* lm_b1 = (const float*)d_in[2];
  const float* lm_W2 = (const float*)d_in[3];
  const float* lm_b2 = (const float*)d_in[4];
  const float* lm_W3 = (const float*)d_in[5];
  const float* lm_b3 = (const float*)d_in[6];
  const float* gWih  = (const float*)d_in[7];
  const float* gWhh  = (const float*)d_in[8];
  const float* gbih  = (const float*)d_in[9];
  const float* gbhh  = (const float*)d_in[10];
  const float* sW1   = (const float*)d_in[11];
  const float* sb1   = (const float*)d_in[12];
  const float* sW2   = (const float*)d_in[13];
  const float* sb2   = (const float*)d_in[14];
  const float* sW3   = (const float*)d_in[15];
  const float* sb3   = (const float*)d_in[16];
  float* out = (float*)d_out;

  float* H1 = (float*)d_ws;                                       // 128*100*512 f32
  float* H2 = (float*)((char*)d_ws + (size_t)BB * NN * 512 * 4);  // 128*100*256 f32

  k_lm1<<<dim3(4, NN), 512, 0, stream>>>(x, lm_W1, lm_b1, H1);
  k_lm2<<<dim3(NN, 8), 256, 0, stream>>>(H1, lm_W2, lm_b2, H2);
  k_lm3<<<dim3(3200), 256, 0, stream>>>(H2, lm_W3, lm_b3, out);
  k_gru<<<dim3(32, NN), 64, 0, stream>>>(x, gWih, gWhh, gbih, gbhh,
                                         sW1, sb1, sW2, sb2, sW3, sb3, out);
}